// Round 1
// baseline (12593.993 us; speedup 1.0000x reference)
//
#include <hip/hip_runtime.h>
#include <math.h>

#define DEV __device__ __forceinline__

DEV float lrelu_f(float v) { return v > 0.f ? v : 0.1f * v; }

// ---------------------------------------------------------------------------
// Weight transpose: src [L][O][KK] -> dst [L][KK][O]
// ---------------------------------------------------------------------------
__global__ void transpose_w(const float* __restrict__ src, float* __restrict__ dst,
                            int L, int O, int KK) {
    int idx = blockIdx.x * 256 + threadIdx.x;
    int tot = L * O * KK;
    if (idx >= tot) return;
    int l = idx / (O * KK);
    int r = idx - l * (O * KK);
    int o = r / KK;
    int k = r - o * KK;
    dst[((size_t)l * KK + k) * O + o] = src[idx];
}

// ---------------------------------------------------------------------------
// kv = lrelu(k_v @ comp_w.T)   k_v:[16,256], comp_w:[64,256] -> kv:[16,64]
// ---------------------------------------------------------------------------
__global__ void kv_kernel(const float* __restrict__ kvin, const float* __restrict__ comp_w,
                          float* __restrict__ kv) {
    int b = blockIdx.x, c = threadIdx.x;
    const float* a = kvin + b * 256;
    const float* w = comp_w + c * 256;
    float s = 0.f;
    for (int m = 0; m < 256; ++m) s += a[m] * w[m];
    kv[b * 64 + c] = lrelu_f(s);
}

// ---------------------------------------------------------------------------
// Per-(layer,batch) dynamic kernel + CA attention precompute.
// grid = 50*16 blocks, 64 threads.
//   t1  = lrelu(kv @ kw1.T)            kw1[l]: [64,64]
//   ker = t1 @ kw2.T                   kw2[l]: [576,64]  (576 = c*9+tap)
//   a1  = lrelu(kv @ caw1.T)           caw1[l]: [8,64]
//   att = sigmoid(a1 @ caw2.T)         caw2[l]: [64,8]
// ker stored transposed: ker_all[l][b][tap][c]; att_all[l][b][c]
// ---------------------------------------------------------------------------
__global__ void kerprep(const float* __restrict__ kv, const float* __restrict__ kw1,
                        const float* __restrict__ kw2, const float* __restrict__ caw1,
                        const float* __restrict__ caw2, float* __restrict__ ker_all,
                        float* __restrict__ att_all) {
    int l = blockIdx.x >> 4;
    int b = blockIdx.x & 15;
    int c = threadIdx.x;
    __shared__ float kvb[64];
    __shared__ float t1[64];
    __shared__ float a1[8];
    kvb[c] = kv[b * 64 + c];
    __syncthreads();

    {
        const float* w1 = kw1 + (size_t)l * 64 * 64 + c * 64;
        float s = 0.f;
        for (int j = 0; j < 64; ++j) s += kvb[j] * w1[j];
        t1[c] = lrelu_f(s);
    }
    if (c < 8) {
        const float* cw1 = caw1 + (size_t)l * 8 * 64 + c * 64;
        float s = 0.f;
        for (int j = 0; j < 64; ++j) s += kvb[j] * cw1[j];
        a1[c] = lrelu_f(s);
    }
    __syncthreads();

    const float* w2 = kw2 + (size_t)l * 576 * 64;
    for (int t = 0; t < 9; ++t) {
        const float* row = w2 + (size_t)(c * 9 + t) * 64;
        float s = 0.f;
        for (int j = 0; j < 64; ++j) s += t1[j] * row[j];
        ker_all[(((size_t)l * 16 + b) * 9 + t) * 64 + c] = s;
    }
    {
        const float* c2 = caw2 + (size_t)l * 64 * 8 + c * 8;
        float s = 0.f;
        for (int r = 0; r < 8; ++r) s += a1[r] * c2[r];
        att_all[((size_t)l * 16 + b) * 64 + c] = 1.f / (1.f + expf(-s));
    }
}

// ---------------------------------------------------------------------------
// Head conv: x NCHW [16,3,64,64] -> x0,res NHWC [16,64,64,64]; wt:[27][64]
// Block: 256 thr = 64 co x 4 groups of 8 px; block covers 32-px row segment.
// ---------------------------------------------------------------------------
__global__ __launch_bounds__(256) void head_conv(const float* __restrict__ x,
                                                 const float* __restrict__ wt,
                                                 const float* __restrict__ bias,
                                                 float* __restrict__ x0,
                                                 float* __restrict__ res) {
    int t = threadIdx.x;
    int co = t & 63, q = t >> 6;
    int bid = blockIdx.x;
    int b = bid >> 7;
    int rem = bid & 127;
    int y = rem >> 1;
    int xs = (rem & 1) * 32 + q * 8;

    float bv = bias[co];
    float acc[8];
#pragma unroll
    for (int p = 0; p < 8; ++p) acc[p] = bv;

    int coff[10];
    bool cok[10];
#pragma unroll
    for (int i = 0; i < 10; ++i) {
        int col = xs - 1 + i;
        cok[i] = (col >= 0) && (col < 64);
        coff[i] = cok[i] ? col : 0;
    }

    for (int cin = 0; cin < 3; ++cin) {
#pragma unroll
        for (int ky = 0; ky < 3; ++ky) {
            int row = y + ky - 1;
            bool rok = (row >= 0) && (row < 64);
            const float* rp = x + ((size_t)(b * 3 + cin) * 64 + (rok ? row : 0)) * 64;
            float v[10];
#pragma unroll
            for (int i = 0; i < 10; ++i) v[i] = (rok && cok[i]) ? rp[coff[i]] : 0.f;
            const float* wp = wt + ((cin * 3 + ky) * 3) * 64 + co;
            float w0 = wp[0], w1 = wp[64], w2 = wp[128];
#pragma unroll
            for (int p = 0; p < 8; ++p) acc[p] += w0 * v[p] + w1 * v[p + 1] + w2 * v[p + 2];
        }
    }
    size_t ob = (((size_t)b * 64 + y) * 64 + xs) * 64 + co;
#pragma unroll
    for (int p = 0; p < 8; ++p) {
        x0[ob + (size_t)p * 64] = acc[p];
        res[ob + (size_t)p * 64] = acc[p];
    }
}

// ---------------------------------------------------------------------------
// Main 3x3 conv, 64->64 ch, NHWC. wt:[576][64] ((cin*3+ky)*3+kx major).
// resid: optional residual added at same pixel (in-place safe). act: lrelu.
// Block: 256 thr = 64 co x 4 groups of 8 px (32-px row segment). grid 2048.
// ---------------------------------------------------------------------------
__global__ __launch_bounds__(256) void conv3x3_64(const float* __restrict__ in,
                                                  const float* __restrict__ wt,
                                                  const float* __restrict__ bias,
                                                  const float* __restrict__ resid,
                                                  float* __restrict__ out, int act) {
    int t = threadIdx.x;
    int co = t & 63, q = t >> 6;
    int bid = blockIdx.x;
    int b = bid >> 7;
    int rem = bid & 127;
    int y = rem >> 1;
    int xs = (rem & 1) * 32 + q * 8;

    float bv = bias[co];
    float acc[8];
#pragma unroll
    for (int p = 0; p < 8; ++p) acc[p] = bv;

    int coff[10];
    bool cok[10];
#pragma unroll
    for (int i = 0; i < 10; ++i) {
        int col = xs - 1 + i;
        cok[i] = (col >= 0) && (col < 64);
        coff[i] = (cok[i] ? col : 0) * 64;
    }

    const float* inb = in + (size_t)b * 64 * 64 * 64;

    for (int cin = 0; cin < 64; ++cin) {
#pragma unroll
        for (int ky = 0; ky < 3; ++ky) {
            int row = y + ky - 1;
            bool rok = (row >= 0) && (row < 64);
            const float* rp = inb + (size_t)(rok ? row : 0) * 64 * 64 + cin;
            float v[10];
#pragma unroll
            for (int i = 0; i < 10; ++i) v[i] = (rok && cok[i]) ? rp[coff[i]] : 0.f;
            const float* wp = wt + ((cin * 3 + ky) * 3) * 64 + co;
            float w0 = wp[0], w1 = wp[64], w2 = wp[128];
#pragma unroll
            for (int p = 0; p < 8; ++p) acc[p] += w0 * v[p] + w1 * v[p + 1] + w2 * v[p + 2];
        }
    }

    size_t ob = (((size_t)b * 64 + y) * 64 + xs) * 64 + co;
    if (resid) {
#pragma unroll
        for (int p = 0; p < 8; ++p) acc[p] += resid[ob + (size_t)p * 64];
    }
    if (act) {
#pragma unroll
        for (int p = 0; p < 8; ++p) acc[p] = lrelu_f(acc[p]);
    }
#pragma unroll
    for (int p = 0; p < 8; ++p) out[ob + (size_t)p * 64] = acc[p];
}

// ---------------------------------------------------------------------------
// Fused DA_conv: out = act( 1x1( lrelu(depthwise3x3(in, ker)) ) + cb + in*att )
// kerT: [16][9][64] for this layer; cwT: [cin][o]; att: [16][64]
// Block: 256 thr = 64 ch x 4 groups of 4 px (16-px row segment). grid 4096.
// ---------------------------------------------------------------------------
__global__ __launch_bounds__(256) void da_conv_fused(const float* __restrict__ in,
                                                     const float* __restrict__ kerT,
                                                     const float* __restrict__ cwT,
                                                     const float* __restrict__ cb,
                                                     const float* __restrict__ attv,
                                                     float* __restrict__ out, int act) {
    __shared__ float mid[64][20];  // [c][px(16)+pad], 16B-aligned rows (80B)
    int t = threadIdx.x;
    int c = t & 63, q = t >> 6;
    int bid = blockIdx.x;
    int b = bid >> 8;
    int rem = bid & 255;
    int y = rem >> 2;
    int xs = (rem & 3) * 16 + q * 4;

    // phase 1: depthwise 3x3 for channel c at 4 pixels
    float m[4] = {0.f, 0.f, 0.f, 0.f};
    const float* kb = kerT + (size_t)b * 9 * 64 + c;
    const float* inb = in + (size_t)b * 64 * 64 * 64;
    int coff[6];
    bool cok[6];
#pragma unroll
    for (int i = 0; i < 6; ++i) {
        int col = xs - 1 + i;
        cok[i] = (col >= 0) && (col < 64);
        coff[i] = (cok[i] ? col : 0) * 64;
    }
#pragma unroll
    for (int ky = 0; ky < 3; ++ky) {
        int row = y + ky - 1;
        bool rok = (row >= 0) && (row < 64);
        const float* rp = inb + (size_t)(rok ? row : 0) * 64 * 64 + c;
        float v[6];
#pragma unroll
        for (int i = 0; i < 6; ++i) v[i] = (rok && cok[i]) ? rp[coff[i]] : 0.f;
        float k0 = kb[(ky * 3 + 0) * 64], k1 = kb[(ky * 3 + 1) * 64], k2 = kb[(ky * 3 + 2) * 64];
#pragma unroll
        for (int p = 0; p < 4; ++p) m[p] += k0 * v[p] + k1 * v[p + 1] + k2 * v[p + 2];
    }
#pragma unroll
    for (int p = 0; p < 4; ++p) mid[c][q * 4 + p] = lrelu_f(m[p]);
    __syncthreads();

    // phase 2: 1x1 conv over channels + CA residual
    int o = c;
    float bv = cb[o];
    float a[4] = {bv, bv, bv, bv};
    for (int cin = 0; cin < 64; ++cin) {
        float w = cwT[cin * 64 + o];
        float4 mv = *(const float4*)&mid[cin][q * 4];
        a[0] += w * mv.x;
        a[1] += w * mv.y;
        a[2] += w * mv.z;
        a[3] += w * mv.w;
    }
    float av = attv[b * 64 + o];
    size_t ob = (((size_t)b * 64 + y) * 64 + xs) * 64 + o;
#pragma unroll
    for (int p = 0; p < 4; ++p) {
        float r = a[p] + in[ob + (size_t)p * 64] * av;
        out[ob + (size_t)p * 64] = act ? lrelu_f(r) : r;
    }
}

// ---------------------------------------------------------------------------
// Up conv 64->256 ch + fused pixel shuffle (r=2). in NHWC [16,64,64,64].
// wt:[576][256]. Writes shuf NHWC [16,128,128,64].
// Block: 256 thr = 256 o x 4 px. grid 16384.
// ---------------------------------------------------------------------------
__global__ __launch_bounds__(256) void up_conv(const float* __restrict__ in,
                                               const float* __restrict__ wt,
                                               const float* __restrict__ bias,
                                               float* __restrict__ shuf) {
    int o = threadIdx.x;
    int bid = blockIdx.x;
    int b = bid >> 10;
    int rem = bid & 1023;
    int y = rem >> 4;
    int xs = (rem & 15) * 4;

    float bv = bias[o];
    float acc[4] = {bv, bv, bv, bv};

    int coff[6];
    bool cok[6];
#pragma unroll
    for (int i = 0; i < 6; ++i) {
        int col = xs - 1 + i;
        cok[i] = (col >= 0) && (col < 64);
        coff[i] = (cok[i] ? col : 0) * 64;
    }
    const float* inb = in + (size_t)b * 64 * 64 * 64;

    for (int cin = 0; cin < 64; ++cin) {
#pragma unroll
        for (int ky = 0; ky < 3; ++ky) {
            int row = y + ky - 1;
            bool rok = (row >= 0) && (row < 64);
            const float* rp = inb + (size_t)(rok ? row : 0) * 64 * 64 + cin;
            float v[6];
#pragma unroll
            for (int i = 0; i < 6; ++i) v[i] = (rok && cok[i]) ? rp[coff[i]] : 0.f;
            const float* wp = wt + ((cin * 3 + ky) * 3) * 256 + o;
            float w0 = wp[0], w1 = wp[256], w2 = wp[512];
#pragma unroll
            for (int p = 0; p < 4; ++p) acc[p] += w0 * v[p] + w1 * v[p + 1] + w2 * v[p + 2];
        }
    }

    int ch = o >> 2, r1 = (o >> 1) & 1, r2 = o & 1;
    int yy = 2 * y + r1;
#pragma unroll
    for (int p = 0; p < 4; ++p) {
        int xx = 2 * (xs + p) + r2;
        shuf[(((size_t)b * 128 + yy) * 128 + xx) * 64 + ch] = acc[p];
    }
}

// ---------------------------------------------------------------------------
// Tail conv 64->3 ch on [16,128,128] NHWC -> out NCHW [16,3,128,128].
// wt:[576][3] staged in LDS. Thread per pixel (all 3 outputs). grid 1024.
// ---------------------------------------------------------------------------
__global__ __launch_bounds__(256) void tail_conv(const float* __restrict__ shuf,
                                                 const float* __restrict__ wt,
                                                 const float* __restrict__ bias,
                                                 float* __restrict__ outp) {
    __shared__ float wl[1728];
    for (int i = threadIdx.x; i < 1728; i += 256) wl[i] = wt[i];
    __syncthreads();

    int p = blockIdx.x * 256 + threadIdx.x;
    int b = p >> 14;
    int rem = p & 16383;
    int y = rem >> 7;
    int x = rem & 127;

    float a0 = bias[0], a1 = bias[1], a2 = bias[2];
    const float* sb = shuf + (size_t)b * 128 * 128 * 64;

    for (int ky = 0; ky < 3; ++ky) {
        int row = y + ky - 1;
        bool rok = (row >= 0) && (row < 128);
#pragma unroll
        for (int kx = 0; kx < 3; ++kx) {
            int col = x + kx - 1;
            bool ok = rok && (col >= 0) && (col < 128);
            const float* px = sb + ((size_t)(ok ? row : 0) * 128 + (ok ? col : 0)) * 64;
            int tap = ky * 3 + kx;
            for (int c4 = 0; c4 < 16; ++c4) {
                float4 v = ok ? *(const float4*)(px + c4 * 4) : make_float4(0.f, 0.f, 0.f, 0.f);
#pragma unroll
                for (int j = 0; j < 4; ++j) {
                    float vv = (j == 0) ? v.x : (j == 1) ? v.y : (j == 2) ? v.z : v.w;
                    const float* wp = &wl[((c4 * 4 + j) * 9 + tap) * 3];
                    a0 += vv * wp[0];
                    a1 += vv * wp[1];
                    a2 += vv * wp[2];
                }
            }
        }
    }
    size_t base = (size_t)b * 3 * 16384 + (size_t)y * 128 + x;
    outp[base] = a0;
    outp[base + 16384] = a1;
    outp[base + 2 * 16384] = a2;
}

// ---------------------------------------------------------------------------
extern "C" void kernel_launch(void* const* d_in, const int* in_sizes, int n_in,
                              void* d_out, int out_size, void* d_ws, size_t ws_size,
                              hipStream_t stream) {
    const float* x      = (const float*)d_in[0];
    const float* k_v    = (const float*)d_in[1];
    const float* head_w = (const float*)d_in[2];
    const float* head_b = (const float*)d_in[3];
    const float* comp_w = (const float*)d_in[4];
    const float* da_kw1 = (const float*)d_in[5];
    const float* da_kw2 = (const float*)d_in[6];
    const float* da_cw  = (const float*)d_in[7];
    const float* da_cb  = (const float*)d_in[8];
    const float* ca_w1  = (const float*)d_in[9];
    const float* ca_w2  = (const float*)d_in[10];
    const float* dab_cw = (const float*)d_in[11];
    const float* dab_cb = (const float*)d_in[12];
    const float* grp_w  = (const float*)d_in[13];
    const float* grp_b  = (const float*)d_in[14];
    const float* body_w = (const float*)d_in[15];
    const float* body_b = (const float*)d_in[16];
    const float* up_w   = (const float*)d_in[17];
    const float* up_b   = (const float*)d_in[18];
    const float* tail_w = (const float*)d_in[19];
    const float* tail_b = (const float*)d_in[20];

    float* ws = (float*)d_ws;
    float* wT_dab  = ws; ws += (size_t)50 * 576 * 64;
    float* wT_da   = ws; ws += (size_t)50 * 64 * 64;
    float* wT_grp  = ws; ws += (size_t)5 * 576 * 64;
    float* wT_body = ws; ws += (size_t)576 * 64;
    float* wT_up   = ws; ws += (size_t)576 * 256;
    float* wT_head = ws; ws += (size_t)27 * 64;
    float* wT_tail = ws; ws += (size_t)576 * 4;   // (pad)
    float* kvbuf   = ws; ws += 16 * 64;
    float* ker_all = ws; ws += (size_t)50 * 16 * 9 * 64;
    float* att_all = ws; ws += (size_t)50 * 16 * 64;
    const size_t ACT = (size_t)16 * 64 * 64 * 64;  // 4,194,304
    float* x0   = ws; ws += ACT;
    float* resA = ws; ws += ACT;
    float* resB = ws; ws += ACT;
    float* gin  = ws; ws += ACT;
    float* t0b  = ws; ws += ACT;
    float* t1b  = ws; ws += ACT;
    float* shuf = ws; ws += (size_t)16 * 128 * 128 * 64;

    // --- weight transposes (every call; ws is re-poisoned by harness) ---
    transpose_w<<<(50 * 64 * 576 + 255) / 256, 256, 0, stream>>>(dab_cw, wT_dab, 50, 64, 576);
    transpose_w<<<(50 * 64 * 64 + 255) / 256, 256, 0, stream>>>(da_cw, wT_da, 50, 64, 64);
    transpose_w<<<(5 * 64 * 576 + 255) / 256, 256, 0, stream>>>(grp_w, wT_grp, 5, 64, 576);
    transpose_w<<<(64 * 576 + 255) / 256, 256, 0, stream>>>(body_w, wT_body, 1, 64, 576);
    transpose_w<<<(256 * 576 + 255) / 256, 256, 0, stream>>>(up_w, wT_up, 1, 256, 576);
    transpose_w<<<(64 * 27 + 255) / 256, 256, 0, stream>>>(head_w, wT_head, 1, 64, 27);
    transpose_w<<<(3 * 576 + 255) / 256, 256, 0, stream>>>(tail_w, wT_tail, 1, 3, 576);

    kv_kernel<<<16, 64, 0, stream>>>(k_v, comp_w, kvbuf);
    kerprep<<<50 * 16, 64, 0, stream>>>(kvbuf, da_kw1, da_kw2, ca_w1, ca_w2, ker_all, att_all);

    head_conv<<<2048, 256, 0, stream>>>(x, wT_head, head_b, x0, resA);

    float* cur = resA;
    float* oth = resB;
    for (int g = 0; g < 5; ++g) {
        hipMemcpyAsync(gin, cur, ACT * sizeof(float), hipMemcpyDeviceToDevice, stream);
        for (int n = 0; n < 5; ++n) {
            int l0 = (g * 5 + n) * 2, l1 = l0 + 1;
            da_conv_fused<<<4096, 256, 0, stream>>>(
                cur, ker_all + (size_t)l0 * 16 * 9 * 64, wT_da + (size_t)l0 * 64 * 64,
                da_cb + (size_t)l0 * 64, att_all + (size_t)l0 * 16 * 64, t0b, 1);
            conv3x3_64<<<2048, 256, 0, stream>>>(
                t0b, wT_dab + (size_t)l0 * 576 * 64, dab_cb + (size_t)l0 * 64, nullptr, t1b, 1);
            da_conv_fused<<<4096, 256, 0, stream>>>(
                t1b, ker_all + (size_t)l1 * 16 * 9 * 64, wT_da + (size_t)l1 * 64 * 64,
                da_cb + (size_t)l1 * 64, att_all + (size_t)l1 * 16 * 64, t0b, 1);
            conv3x3_64<<<2048, 256, 0, stream>>>(
                t0b, wT_dab + (size_t)l1 * 576 * 64, dab_cb + (size_t)l1 * 64, cur, cur, 0);
        }
        conv3x3_64<<<2048, 256, 0, stream>>>(
            cur, wT_grp + (size_t)g * 576 * 64, grp_b + (size_t)g * 64, gin, oth, 0);
        float* tmp = cur; cur = oth; oth = tmp;
    }
    conv3x3_64<<<2048, 256, 0, stream>>>(cur, wT_body, body_b, x0, oth, 0);
    cur = oth;

    up_conv<<<16384, 256, 0, stream>>>(cur, wT_up, up_b, shuf);
    tail_conv<<<1024, 256, 0, stream>>>(shuf, wT_tail, tail_b, (float*)d_out);
}

// Round 2
// 2246.575 us; speedup vs baseline: 5.6059x; 5.6059x over previous
//
#include <hip/hip_runtime.h>
#include <math.h>

#define DEV __device__ __forceinline__

DEV float lrelu_f(float v) { return v > 0.f ? v : 0.1f * v; }

DEV unsigned short f2bf(float f) {
    unsigned u = __builtin_bit_cast(unsigned, f);
    unsigned r = u + 0x7FFFu + ((u >> 16) & 1u);
    return (unsigned short)(r >> 16);
}

typedef __attribute__((ext_vector_type(8))) short bh8;
typedef __attribute__((ext_vector_type(16))) float f16acc;

#define MFMA32(acc, a, b) acc = __builtin_amdgcn_mfma_f32_32x32x16_bf16(a, b, acc, 0, 0, 0)

// ---------------------------------------------------------------------------
// Weight transpose: src [L][O][KK] -> dst [L][KK][O]  (head/tail only)
// ---------------------------------------------------------------------------
__global__ void transpose_w(const float* __restrict__ src, float* __restrict__ dst,
                            int L, int O, int KK) {
    int idx = blockIdx.x * 256 + threadIdx.x;
    int tot = L * O * KK;
    if (idx >= tot) return;
    int l = idx / (O * KK);
    int r = idx - l * (O * KK);
    int o = r / KK;
    int k = r - o * KK;
    dst[((size_t)l * KK + k) * O + o] = src[idx];
}

// ---------------------------------------------------------------------------
// Pack 3x3 conv weights [L][64 o][64 cin][3][3] -> frag layout
// [L][36 kchunk][2 ntile][64 lane][8 j] bf16, k = tap*64+cin, o = nt*32+(lane&31)
// ---------------------------------------------------------------------------
__global__ void pack3x3(const float* __restrict__ src, unsigned short* __restrict__ dst, int L) {
    int idx = blockIdx.x * 256 + threadIdx.x;
    if (idx >= L * 4608) return;
    int l = idx / 4608;
    int r = idx - l * 4608;
    int c = r >> 7;
    int rr = r & 127;
    int nt = rr >> 6, lane = rr & 63;
    int o = nt * 32 + (lane & 31);
    int kg = lane >> 5;
    unsigned short v[8];
#pragma unroll
    for (int j = 0; j < 8; ++j) {
        int k = c * 16 + kg * 8 + j;
        int t = k >> 6, cin = k & 63;
        v[j] = f2bf(src[(((size_t)l * 64 + o) * 64 + cin) * 9 + t]);
    }
    uint4 u;
    u.x = v[0] | ((unsigned)v[1] << 16);
    u.y = v[2] | ((unsigned)v[3] << 16);
    u.z = v[4] | ((unsigned)v[5] << 16);
    u.w = v[6] | ((unsigned)v[7] << 16);
    *(uint4*)(dst + (size_t)idx * 8) = u;
}

// ---------------------------------------------------------------------------
// Pack da 1x1 weights [L][64 o][64 cin] -> [L][4][2][64][8] bf16, k = cin
// ---------------------------------------------------------------------------
__global__ void pack_da(const float* __restrict__ src, unsigned short* __restrict__ dst, int L) {
    int idx = blockIdx.x * 256 + threadIdx.x;
    if (idx >= L * 512) return;
    int l = idx >> 9;
    int r = idx & 511;
    int c = r >> 7;
    int rr = r & 127;
    int nt = rr >> 6, lane = rr & 63;
    int o = nt * 32 + (lane & 31);
    int kg = lane >> 5;
    unsigned short v[8];
#pragma unroll
    for (int j = 0; j < 8; ++j) {
        int cin = c * 16 + kg * 8 + j;
        v[j] = f2bf(src[((size_t)l * 64 + o) * 64 + cin]);
    }
    uint4 u;
    u.x = v[0] | ((unsigned)v[1] << 16);
    u.y = v[2] | ((unsigned)v[3] << 16);
    u.z = v[4] | ((unsigned)v[5] << 16);
    u.w = v[6] | ((unsigned)v[7] << 16);
    *(uint4*)(dst + (size_t)idx * 8) = u;
}

// ---------------------------------------------------------------------------
// Pack up conv weights [256 o][64 cin][3][3] -> [36][8][64][8] bf16
// ---------------------------------------------------------------------------
__global__ void pack_up(const float* __restrict__ src, unsigned short* __restrict__ dst) {
    int idx = blockIdx.x * 256 + threadIdx.x;
    if (idx >= 18432) return;
    int c = idx >> 9;
    int nt = (idx >> 6) & 7;
    int lane = idx & 63;
    int o = nt * 32 + (lane & 31);
    int kg = lane >> 5;
    unsigned short v[8];
#pragma unroll
    for (int j = 0; j < 8; ++j) {
        int k = c * 16 + kg * 8 + j;
        int t = k >> 6, cin = k & 63;
        v[j] = f2bf(src[((size_t)o * 64 + cin) * 9 + t]);
    }
    uint4 u;
    u.x = v[0] | ((unsigned)v[1] << 16);
    u.y = v[2] | ((unsigned)v[3] << 16);
    u.z = v[4] | ((unsigned)v[5] << 16);
    u.w = v[6] | ((unsigned)v[7] << 16);
    *(uint4*)(dst + (size_t)idx * 8) = u;
}

// ---------------------------------------------------------------------------
// kv = lrelu(k_v @ comp_w.T)
// ---------------------------------------------------------------------------
__global__ void kv_kernel(const float* __restrict__ kvin, const float* __restrict__ comp_w,
                          float* __restrict__ kv) {
    int b = blockIdx.x, c = threadIdx.x;
    const float* a = kvin + b * 256;
    const float* w = comp_w + c * 256;
    float s = 0.f;
    for (int m = 0; m < 256; ++m) s += a[m] * w[m];
    kv[b * 64 + c] = lrelu_f(s);
}

// ---------------------------------------------------------------------------
// Per-(layer,batch) dynamic kernel + CA attention precompute (as round 1).
// ker_all[l][b][tap][c]; att_all[l][b][c]
// ---------------------------------------------------------------------------
__global__ void kerprep(const float* __restrict__ kv, const float* __restrict__ kw1,
                        const float* __restrict__ kw2, const float* __restrict__ caw1,
                        const float* __restrict__ caw2, float* __restrict__ ker_all,
                        float* __restrict__ att_all) {
    int l = blockIdx.x >> 4;
    int b = blockIdx.x & 15;
    int c = threadIdx.x;
    __shared__ float kvb[64];
    __shared__ float t1[64];
    __shared__ float a1[8];
    kvb[c] = kv[b * 64 + c];
    __syncthreads();
    {
        const float* w1 = kw1 + (size_t)l * 4096 + c * 64;
        float s = 0.f;
        for (int j = 0; j < 64; ++j) s += kvb[j] * w1[j];
        t1[c] = lrelu_f(s);
    }
    if (c < 8) {
        const float* cw1 = caw1 + (size_t)l * 512 + c * 64;
        float s = 0.f;
        for (int j = 0; j < 64; ++j) s += kvb[j] * cw1[j];
        a1[c] = lrelu_f(s);
    }
    __syncthreads();
    const float* w2 = kw2 + (size_t)l * 576 * 64;
    for (int t = 0; t < 9; ++t) {
        const float* row = w2 + (size_t)(c * 9 + t) * 64;
        float s = 0.f;
        for (int j = 0; j < 64; ++j) s += t1[j] * row[j];
        ker_all[(((size_t)l * 16 + b) * 9 + t) * 64 + c] = s;
    }
    {
        const float* c2 = caw2 + (size_t)l * 512 + c * 8;
        float s = 0.f;
        for (int r = 0; r < 8; ++r) s += a1[r] * c2[r];
        att_all[((size_t)l * 16 + b) * 64 + c] = 1.f / (1.f + expf(-s));
    }
}

// ---------------------------------------------------------------------------
// Head conv: x NCHW [16,3,64,64] -> x0,res NHWC; wt:[27][64] (fp32 vector)
// ---------------------------------------------------------------------------
__global__ __launch_bounds__(256) void head_conv(const float* __restrict__ x,
                                                 const float* __restrict__ wt,
                                                 const float* __restrict__ bias,
                                                 float* __restrict__ x0,
                                                 float* __restrict__ res) {
    int t = threadIdx.x;
    int co = t & 63, q = t >> 6;
    int bid = blockIdx.x;
    int b = bid >> 7;
    int rem = bid & 127;
    int y = rem >> 1;
    int xs = (rem & 1) * 32 + q * 8;

    float bv = bias[co];
    float acc[8];
#pragma unroll
    for (int p = 0; p < 8; ++p) acc[p] = bv;

    int coff[10];
    bool cok[10];
#pragma unroll
    for (int i = 0; i < 10; ++i) {
        int col = xs - 1 + i;
        cok[i] = (col >= 0) && (col < 64);
        coff[i] = cok[i] ? col : 0;
    }
    for (int cin = 0; cin < 3; ++cin) {
#pragma unroll
        for (int ky = 0; ky < 3; ++ky) {
            int row = y + ky - 1;
            bool rok = (row >= 0) && (row < 64);
            const float* rp = x + ((size_t)(b * 3 + cin) * 64 + (rok ? row : 0)) * 64;
            float v[10];
#pragma unroll
            for (int i = 0; i < 10; ++i) v[i] = (rok && cok[i]) ? rp[coff[i]] : 0.f;
            const float* wp = wt + ((cin * 3 + ky) * 3) * 64 + co;
            float w0 = wp[0], w1 = wp[64], w2 = wp[128];
#pragma unroll
            for (int p = 0; p < 8; ++p) acc[p] += w0 * v[p] + w1 * v[p + 1] + w2 * v[p + 2];
        }
    }
    size_t ob = (((size_t)b * 64 + y) * 64 + xs) * 64 + co;
#pragma unroll
    for (int p = 0; p < 8; ++p) {
        x0[ob + (size_t)p * 64] = acc[p];
        res[ob + (size_t)p * 64] = acc[p];
    }
}

// ---------------------------------------------------------------------------
// MFMA 3x3 conv 64->64, NHWC fp32 in/out, bf16 compute.
// Block: 256 thr = 4 waves; tile 16x16 px; halo 18x18 staged to LDS bf16
// (pixel stride 72). Wave w: px [w*64, w*64+64) as 2 M-tiles x 2 N-tiles.
// Grid: 256 (b=bid>>4, ty=(bid>>2)&3, tx=bid&3).
// ---------------------------------------------------------------------------
__global__ __launch_bounds__(256) void conv3x3_mfma(const float* __restrict__ in,
                                                    const unsigned short* __restrict__ wp,
                                                    const float* __restrict__ bias,
                                                    const float* __restrict__ resid,
                                                    float* __restrict__ out, int act) {
    __shared__ unsigned short sm[324 * 72];
    int tid = threadIdx.x;
    int bid = blockIdx.x;
    int b = bid >> 4, ty = (bid >> 2) & 3, tx = bid & 3;
    const float* inb = in + (size_t)b * 262144;

    for (int i = tid; i < 5184; i += 256) {
        int px = i >> 4, c4 = i & 15;
        int hy = px / 18, hx = px - hy * 18;
        int row = ty * 16 + hy - 1, col = tx * 16 + hx - 1;
        float4 v = make_float4(0.f, 0.f, 0.f, 0.f);
        if (row >= 0 && row < 64 && col >= 0 && col < 64)
            v = *(const float4*)(inb + (((size_t)row * 64 + col) * 64 + c4 * 4));
        uint2 u;
        u.x = f2bf(v.x) | ((unsigned)f2bf(v.y) << 16);
        u.y = f2bf(v.z) | ((unsigned)f2bf(v.w) << 16);
        *(uint2*)&sm[px * 72 + c4 * 4] = u;
    }
    __syncthreads();

    int lane = tid & 63, w = tid >> 6;
    int l31 = lane & 31, kg8 = (lane >> 5) * 8;
    int mbase = w * 64;
    int p0 = mbase + l31;
    int ly0 = p0 >> 4, lx0 = p0 & 15;

    f16acc a00 = {0,0,0,0,0,0,0,0,0,0,0,0,0,0,0,0};
    f16acc a01 = a00, a10 = a00, a11 = a00;

    for (int t = 0; t < 9; ++t) {
        int tyt = t / 3, txt = t - tyt * 3;
        int base0 = ((ly0 + tyt) * 18 + lx0 + txt) * 72 + kg8;
        int base1 = base0 + 2592;  // +32 px = +2 halo rows
#pragma unroll
        for (int cc = 0; cc < 4; ++cc) {
            int c = t * 4 + cc;
            bh8 A0 = *(const bh8*)&sm[base0 + cc * 16];
            bh8 A1 = *(const bh8*)&sm[base1 + cc * 16];
            bh8 B0 = *(const bh8*)&wp[((size_t)(c * 2 + 0) * 64 + lane) * 8];
            bh8 B1 = *(const bh8*)&wp[((size_t)(c * 2 + 1) * 64 + lane) * 8];
            MFMA32(a00, A0, B0);
            MFMA32(a01, A0, B1);
            MFMA32(a10, A1, B0);
            MFMA32(a11, A1, B1);
        }
    }

    float bias0 = bias[l31], bias1 = bias[32 + l31];
    int hi = lane >> 5;
    size_t outb = (size_t)b * 262144;
#pragma unroll
    for (int r = 0; r < 16; ++r) {
        int rowm = (r & 3) + 8 * (r >> 2) + 4 * hi;
        int m0 = mbase + rowm;
        int gy0 = ty * 16 + (m0 >> 4), gx0 = tx * 16 + (m0 & 15);
        size_t i0 = outb + (((size_t)gy0 * 64 + gx0) * 64);
        int m1 = m0 + 32;
        int gy1 = ty * 16 + (m1 >> 4), gx1 = tx * 16 + (m1 & 15);
        size_t i1 = outb + (((size_t)gy1 * 64 + gx1) * 64);
        float v00 = a00[r] + bias0, v01 = a01[r] + bias1;
        float v10 = a10[r] + bias0, v11 = a11[r] + bias1;
        if (resid) {
            v00 += resid[i0 + l31];
            v01 += resid[i0 + 32 + l31];
            v10 += resid[i1 + l31];
            v11 += resid[i1 + 32 + l31];
        }
        if (act) {
            v00 = lrelu_f(v00); v01 = lrelu_f(v01);
            v10 = lrelu_f(v10); v11 = lrelu_f(v11);
        }
        out[i0 + l31] = v00;
        out[i0 + 32 + l31] = v01;
        out[i1 + l31] = v10;
        out[i1 + 32 + l31] = v11;
    }
}

// ---------------------------------------------------------------------------
// Fused DA_conv (MFMA): depthwise 3x3 (fp32, per-sample kernel) -> lrelu ->
// bf16 LDS -> 1x1 MFMA GEMM -> +cb + in*att -> lrelu.
// Block 256 thr, tile 16x16 px. Grid 256.
// ---------------------------------------------------------------------------
__global__ __launch_bounds__(256) void da_mfma(const float* __restrict__ in,
                                               const unsigned short* __restrict__ wp,
                                               const float* __restrict__ cb,
                                               const float* __restrict__ kerT,
                                               const float* __restrict__ attv,
                                               float* __restrict__ out) {
    __shared__ unsigned short mid[256 * 72];
    int tid = threadIdx.x;
    int bid = blockIdx.x;
    int b = bid >> 4, ty = (bid >> 2) & 3, tx = bid & 3;
    const float* inb = in + (size_t)b * 262144;

    // phase 1: depthwise, thread = (c, q); rows ly = q*4 .. q*4+3
    {
        int c = tid & 63, q = tid >> 6;
        const float* kb = kerT + (size_t)b * 576;
        float k[9];
#pragma unroll
        for (int t = 0; t < 9; ++t) k[t] = kb[t * 64 + c];
        for (int rr = 0; rr < 4; ++rr) {
            int ly = q * 4 + rr;
            int gy = ty * 16 + ly;
            float m[16];
#pragma unroll
            for (int xx = 0; xx < 16; ++xx) m[xx] = 0.f;
#pragma unroll
            for (int ky = 0; ky < 3; ++ky) {
                int row = gy + ky - 1;
                bool rok = (row >= 0) && (row < 64);
                const float* rp = inb + (size_t)(rok ? row : 0) * 4096 + c;
                float v[18];
#pragma unroll
                for (int i = 0; i < 18; ++i) {
                    int col = tx * 16 - 1 + i;
                    bool ok = rok && col >= 0 && col < 64;
                    v[i] = ok ? rp[(size_t)col * 64] : 0.f;
                }
                float k0 = k[ky * 3], k1 = k[ky * 3 + 1], k2 = k[ky * 3 + 2];
#pragma unroll
                for (int xx = 0; xx < 16; ++xx) m[xx] += k0 * v[xx] + k1 * v[xx + 1] + k2 * v[xx + 2];
            }
#pragma unroll
            for (int xx = 0; xx < 16; ++xx)
                mid[(ly * 16 + xx) * 72 + c] = f2bf(lrelu_f(m[xx]));
        }
    }
    __syncthreads();

    // phase 2: 1x1 MFMA, K=64
    int lane = tid & 63, w = tid >> 6;
    int l31 = lane & 31, kg8 = (lane >> 5) * 8;
    int mbase = w * 64;
    int base0 = (mbase + l31) * 72 + kg8;
    int base1 = base0 + 32 * 72;

    f16acc a00 = {0,0,0,0,0,0,0,0,0,0,0,0,0,0,0,0};
    f16acc a01 = a00, a10 = a00, a11 = a00;
#pragma unroll
    for (int cc = 0; cc < 4; ++cc) {
        bh8 A0 = *(const bh8*)&mid[base0 + cc * 16];
        bh8 A1 = *(const bh8*)&mid[base1 + cc * 16];
        bh8 B0 = *(const bh8*)&wp[((size_t)(cc * 2 + 0) * 64 + lane) * 8];
        bh8 B1 = *(const bh8*)&wp[((size_t)(cc * 2 + 1) * 64 + lane) * 8];
        MFMA32(a00, A0, B0);
        MFMA32(a01, A0, B1);
        MFMA32(a10, A1, B0);
        MFMA32(a11, A1, B1);
    }

    float cb0 = cb[l31], cb1 = cb[32 + l31];
    float at0 = attv[b * 64 + l31], at1 = attv[b * 64 + 32 + l31];
    int hi = lane >> 5;
    size_t outb = (size_t)b * 262144;
#pragma unroll
    for (int r = 0; r < 16; ++r) {
        int rowm = (r & 3) + 8 * (r >> 2) + 4 * hi;
        int m0 = mbase + rowm;
        int gy0 = ty * 16 + (m0 >> 4), gx0 = tx * 16 + (m0 & 15);
        size_t i0 = outb + (((size_t)gy0 * 64 + gx0) * 64);
        int m1 = m0 + 32;
        int gy1 = ty * 16 + (m1 >> 4), gx1 = tx * 16 + (m1 & 15);
        size_t i1 = outb + (((size_t)gy1 * 64 + gx1) * 64);
        float v00 = a00[r] + cb0 + in[i0 + l31] * at0;
        float v01 = a01[r] + cb1 + in[i0 + 32 + l31] * at1;
        float v10 = a10[r] + cb0 + in[i1 + l31] * at0;
        float v11 = a11[r] + cb1 + in[i1 + 32 + l31] * at1;
        out[i0 + l31] = lrelu_f(v00);
        out[i0 + 32 + l31] = lrelu_f(v01);
        out[i1 + l31] = lrelu_f(v10);
        out[i1 + 32 + l31] = lrelu_f(v11);
    }
}

// ---------------------------------------------------------------------------
// Up conv 64->256 (MFMA) + fused pixel shuffle. Tile 8x8 px, halo 10x10.
// Wave w: co [w*64, w*64+64). Grid 1024.
// ---------------------------------------------------------------------------
__global__ __launch_bounds__(256) void up_mfma(const float* __restrict__ in,
                                               const unsigned short* __restrict__ wp,
                                               const float* __restrict__ bias,
                                               float* __restrict__ shuf) {
    __shared__ unsigned short sm[100 * 72];
    int tid = threadIdx.x;
    int bid = blockIdx.x;
    int b = bid >> 6;
    int t6 = bid & 63;
    int ty = t6 >> 3, tx = t6 & 7;
    const float* inb = in + (size_t)b * 262144;

    for (int i = tid; i < 1600; i += 256) {
        int px = i >> 4, c4 = i & 15;
        int hy = px / 10, hx = px - hy * 10;
        int row = ty * 8 + hy - 1, col = tx * 8 + hx - 1;
        float4 v = make_float4(0.f, 0.f, 0.f, 0.f);
        if (row >= 0 && row < 64 && col >= 0 && col < 64)
            v = *(const float4*)(inb + (((size_t)row * 64 + col) * 64 + c4 * 4));
        uint2 u;
        u.x = f2bf(v.x) | ((unsigned)f2bf(v.y) << 16);
        u.y = f2bf(v.z) | ((unsigned)f2bf(v.w) << 16);
        *(uint2*)&sm[px * 72 + c4 * 4] = u;
    }
    __syncthreads();

    int lane = tid & 63, w = tid >> 6;
    int l31 = lane & 31, kg8 = (lane >> 5) * 8;
    int ly0 = l31 >> 3, lx0 = l31 & 7;

    f16acc a00 = {0,0,0,0,0,0,0,0,0,0,0,0,0,0,0,0};
    f16acc a01 = a00, a10 = a00, a11 = a00;

    for (int t = 0; t < 9; ++t) {
        int tyt = t / 3, txt = t - tyt * 3;
        int base0 = ((ly0 + tyt) * 10 + lx0 + txt) * 72 + kg8;
        int base1 = base0 + 2880;  // +32 px = +4 halo rows
#pragma unroll
        for (int cc = 0; cc < 4; ++cc) {
            int c = t * 4 + cc;
            bh8 A0 = *(const bh8*)&sm[base0 + cc * 16];
            bh8 A1 = *(const bh8*)&sm[base1 + cc * 16];
            bh8 B0 = *(const bh8*)&wp[((size_t)(c * 8 + w * 2 + 0) * 64 + lane) * 8];
            bh8 B1 = *(const bh8*)&wp[((size_t)(c * 8 + w * 2 + 1) * 64 + lane) * 8];
            MFMA32(a00, A0, B0);
            MFMA32(a01, A0, B1);
            MFMA32(a10, A1, B0);
            MFMA32(a11, A1, B1);
        }
    }

    int co0 = w * 64 + l31, co1 = co0 + 32;
    float bias0 = bias[co0], bias1 = bias[co1];
    int ch0 = co0 >> 2, r10 = (co0 >> 1) & 1, r20 = co0 & 1;
    int ch1 = co1 >> 2, r11 = (co1 >> 1) & 1, r21 = co1 & 1;
    int hi = lane >> 5;
#pragma unroll
    for (int r = 0; r < 16; ++r) {
        int rowm = (r & 3) + 8 * (r >> 2) + 4 * hi;
#pragma unroll
        for (int mt = 0; mt < 2; ++mt) {
            int m = mt * 32 + rowm;
            int y = ty * 8 + (m >> 3), x = tx * 8 + (m & 7);
            float va = (mt == 0) ? a00[r] : a10[r];
            float vb = (mt == 0) ? a01[r] : a11[r];
            shuf[(((size_t)b * 128 + 2 * y + r10) * 128 + 2 * x + r20) * 64 + ch0] = va + bias0;
            shuf[(((size_t)b * 128 + 2 * y + r11) * 128 + 2 * x + r21) * 64 + ch1] = vb + bias1;
        }
    }
}

// ---------------------------------------------------------------------------
// Tail conv 64->3 on [16,128,128] NHWC -> NCHW out. Tile 8x8 px, halo 10x10
// staged bf16 (stride 68). Thread = (px, oc); oc=3 wave idles post-staging.
// Grid 4096.
// ---------------------------------------------------------------------------
__global__ __launch_bounds__(256) void tail_conv2(const float* __restrict__ shuf,
                                                  const float* __restrict__ wt,
                                                  const float* __restrict__ bias,
                                                  float* __restrict__ outp) {
    __shared__ unsigned short sv[100 * 68];
    __shared__ float wl[1728];
    int tid = threadIdx.x;
    int bid = blockIdx.x;
    int b = bid >> 8, ty = (bid >> 4) & 15, tx = bid & 15;
    const float* sb = shuf + (size_t)b * 128 * 128 * 64;

    for (int i = tid; i < 1728; i += 256) wl[i] = wt[i];
    for (int i = tid; i < 1600; i += 256) {
        int px = i >> 4, c4 = i & 15;
        int hy = px / 10, hx = px - hy * 10;
        int row = ty * 8 + hy - 1, col = tx * 8 + hx - 1;
        float4 v = make_float4(0.f, 0.f, 0.f, 0.f);
        if (row >= 0 && row < 128 && col >= 0 && col < 128)
            v = *(const float4*)(sb + (((size_t)row * 128 + col) * 64 + c4 * 4));
        uint2 u;
        u.x = f2bf(v.x) | ((unsigned)f2bf(v.y) << 16);
        u.y = f2bf(v.z) | ((unsigned)f2bf(v.w) << 16);
        *(uint2*)&sv[px * 68 + c4 * 4] = u;
    }
    __syncthreads();

    int px = tid & 63, oc = tid >> 6;
    if (oc >= 3) return;
    int ly = px >> 3, lx = px & 7;
    float acc = bias[oc];
    for (int t = 0; t < 9; ++t) {
        int tyt = t / 3, txt = t - tyt * 3;
        int base = ((ly + tyt) * 10 + lx + txt) * 68;
#pragma unroll
        for (int c2 = 0; c2 < 32; ++c2) {
            unsigned u = *(const unsigned*)&sv[base + c2 * 2];
            float v0 = __builtin_bit_cast(float, u << 16);
            float v1 = __builtin_bit_cast(float, u & 0xffff0000u);
            acc += v0 * wl[((2 * c2) * 9 + t) * 3 + oc] + v1 * wl[((2 * c2 + 1) * 9 + t) * 3 + oc];
        }
    }
    int gy = ty * 8 + ly, gx = tx * 8 + lx;
    outp[((size_t)b * 3 + oc) * 16384 + (size_t)gy * 128 + gx] = acc;
}

// ---------------------------------------------------------------------------
extern "C" void kernel_launch(void* const* d_in, const int* in_sizes, int n_in,
                              void* d_out, int out_size, void* d_ws, size_t ws_size,
                              hipStream_t stream) {
    const float* x      = (const float*)d_in[0];
    const float* k_v    = (const float*)d_in[1];
    const float* head_w = (const float*)d_in[2];
    const float* head_b = (const float*)d_in[3];
    const float* comp_w = (const float*)d_in[4];
    const float* da_kw1 = (const float*)d_in[5];
    const float* da_kw2 = (const float*)d_in[6];
    const float* da_cw  = (const float*)d_in[7];
    const float* da_cb  = (const float*)d_in[8];
    const float* ca_w1  = (const float*)d_in[9];
    const float* ca_w2  = (const float*)d_in[10];
    const float* dab_cw = (const float*)d_in[11];
    const float* dab_cb = (const float*)d_in[12];
    const float* grp_w  = (const float*)d_in[13];
    const float* grp_b  = (const float*)d_in[14];
    const float* body_w = (const float*)d_in[15];
    const float* body_b = (const float*)d_in[16];
    const float* up_w   = (const float*)d_in[17];
    const float* up_b   = (const float*)d_in[18];
    const float* tail_w = (const float*)d_in[19];
    const float* tail_b = (const float*)d_in[20];

    char* base = (char*)d_ws;
    auto alloc = [&](size_t bytes) -> char* {
        char* p = base;
        base += (bytes + 255) & ~(size_t)255;
        return p;
    };
    unsigned short* wp_dab  = (unsigned short*)alloc((size_t)50 * 36864 * 2);
    unsigned short* wp_grp  = (unsigned short*)alloc((size_t)5 * 36864 * 2);
    unsigned short* wp_body = (unsigned short*)alloc((size_t)36864 * 2);
    unsigned short* wp_up   = (unsigned short*)alloc((size_t)147456 * 2);
    unsigned short* wp_da   = (unsigned short*)alloc((size_t)50 * 4096 * 2);
    float* wT_head = (float*)alloc(1728 * 4);
    float* wT_tail = (float*)alloc(1728 * 4);
    float* kvbuf   = (float*)alloc(1024 * 4);
    float* ker_all = (float*)alloc((size_t)460800 * 4);
    float* att_all = (float*)alloc((size_t)51200 * 4);
    const size_t ACT = (size_t)16 * 64 * 64 * 64;
    float* x0   = (float*)alloc(ACT * 4);
    float* resA = (float*)alloc(ACT * 4);
    float* resB = (float*)alloc(ACT * 4);
    float* gin  = (float*)alloc(ACT * 4);
    float* t0b  = (float*)alloc(ACT * 4);
    float* t1b  = (float*)alloc(ACT * 4);
    float* shuf = (float*)alloc((size_t)16 * 128 * 128 * 64 * 4);

    pack3x3<<<900, 256, 0, stream>>>(dab_cw, wp_dab, 50);
    pack3x3<<<90, 256, 0, stream>>>(grp_w, wp_grp, 5);
    pack3x3<<<18, 256, 0, stream>>>(body_w, wp_body, 1);
    pack_da<<<100, 256, 0, stream>>>(da_cw, wp_da, 50);
    pack_up<<<72, 256, 0, stream>>>(up_w, wp_up);
    transpose_w<<<7, 256, 0, stream>>>(head_w, wT_head, 1, 64, 27);
    transpose_w<<<7, 256, 0, stream>>>(tail_w, wT_tail, 1, 3, 576);

    kv_kernel<<<16, 64, 0, stream>>>(k_v, comp_w, kvbuf);
    kerprep<<<800, 64, 0, stream>>>(kvbuf, da_kw1, da_kw2, ca_w1, ca_w2, ker_all, att_all);

    head_conv<<<2048, 256, 0, stream>>>(x, wT_head, head_b, x0, resA);

    float* cur = resA;
    float* oth = resB;
    for (int g = 0; g < 5; ++g) {
        hipMemcpyAsync(gin, cur, ACT * sizeof(float), hipMemcpyDeviceToDevice, stream);
        for (int n = 0; n < 5; ++n) {
            int l0 = (g * 5 + n) * 2, l1 = l0 + 1;
            da_mfma<<<256, 256, 0, stream>>>(cur, wp_da + (size_t)l0 * 4096,
                                             da_cb + (size_t)l0 * 64, ker_all + (size_t)l0 * 9216,
                                             att_all + (size_t)l0 * 1024, t0b);
            conv3x3_mfma<<<256, 256, 0, stream>>>(t0b, wp_dab + (size_t)l0 * 36864,
                                                  dab_cb + (size_t)l0 * 64, nullptr, t1b, 1);
            da_mfma<<<256, 256, 0, stream>>>(t1b, wp_da + (size_t)l1 * 4096,
                                             da_cb + (size_t)l1 * 64, ker_all + (size_t)l1 * 9216,
                                             att_all + (size_t)l1 * 1024, t0b);
            conv3x3_mfma<<<256, 256, 0, stream>>>(t0b, wp_dab + (size_t)l1 * 36864,
                                                  dab_cb + (size_t)l1 * 64, cur, cur, 0);
        }
        conv3x3_mfma<<<256, 256, 0, stream>>>(cur, wp_grp + (size_t)g * 36864,
                                              grp_b + (size_t)g * 64, gin, oth, 0);
        float* tmp = cur; cur = oth; oth = tmp;
    }
    conv3x3_mfma<<<256, 256, 0, stream>>>(cur, wp_body, body_b, x0, oth, 0);
    cur = oth;

    up_mfma<<<1024, 256, 0, stream>>>(cur, wp_up, up_b, shuf);
    tail_conv2<<<4096, 256, 0, stream>>>(shuf, wT_tail, tail_b, (float*)d_out);
}

// Round 3
// 1886.646 us; speedup vs baseline: 6.6753x; 1.1908x over previous
//
#include <hip/hip_runtime.h>
#include <math.h>

#define DEV __device__ __forceinline__

DEV float lrelu_f(float v) { return v > 0.f ? v : 0.1f * v; }

DEV unsigned short f2bf(float f) {
    unsigned u = __builtin_bit_cast(unsigned, f);
    unsigned r = u + 0x7FFFu + ((u >> 16) & 1u);
    return (unsigned short)(r >> 16);
}

DEV float bf2f(unsigned short s) {
    return __builtin_bit_cast(float, (unsigned)s << 16);
}

typedef __attribute__((ext_vector_type(8))) short bh8;
typedef __attribute__((ext_vector_type(16))) float f16acc;

#define MFMA32(acc, a, b) acc = __builtin_amdgcn_mfma_f32_32x32x16_bf16(a, b, acc, 0, 0, 0)

// ---------------------------------------------------------------------------
// Weight transpose: src [L][O][KK] -> dst [L][KK][O]  (head only)
// ---------------------------------------------------------------------------
__global__ void transpose_w(const float* __restrict__ src, float* __restrict__ dst,
                            int L, int O, int KK) {
    int idx = blockIdx.x * 256 + threadIdx.x;
    int tot = L * O * KK;
    if (idx >= tot) return;
    int l = idx / (O * KK);
    int r = idx - l * (O * KK);
    int o = r / KK;
    int k = r - o * KK;
    dst[((size_t)l * KK + k) * O + o] = src[idx];
}

// ---------------------------------------------------------------------------
// Pack 3x3 conv weights [L][64 o][64 cin][3][3] -> frag layout
// [L][36 chunk][2 nt][64 lane][8 j] bf16, k = tap*64+cin, o = nt*32+(lane&31)
// ---------------------------------------------------------------------------
__global__ void pack3x3(const float* __restrict__ src, unsigned short* __restrict__ dst, int L) {
    int idx = blockIdx.x * 256 + threadIdx.x;
    if (idx >= L * 4608) return;
    int l = idx / 4608;
    int r = idx - l * 4608;
    int c = r >> 7;
    int rr = r & 127;
    int nt = rr >> 6, lane = rr & 63;
    int o = nt * 32 + (lane & 31);
    int kg = lane >> 5;
    unsigned short v[8];
#pragma unroll
    for (int j = 0; j < 8; ++j) {
        int k = c * 16 + kg * 8 + j;
        int t = k >> 6, cin = k & 63;
        v[j] = f2bf(src[(((size_t)l * 64 + o) * 64 + cin) * 9 + t]);
    }
    uint4 u;
    u.x = v[0] | ((unsigned)v[1] << 16);
    u.y = v[2] | ((unsigned)v[3] << 16);
    u.z = v[4] | ((unsigned)v[5] << 16);
    u.w = v[6] | ((unsigned)v[7] << 16);
    *(uint4*)(dst + (size_t)idx * 8) = u;
}

// ---------------------------------------------------------------------------
// Pack da 1x1 weights [L][64 o][64 cin] -> [L][4 chunk][2 nt][64][8] bf16
// ---------------------------------------------------------------------------
__global__ void pack_da(const float* __restrict__ src, unsigned short* __restrict__ dst, int L) {
    int idx = blockIdx.x * 256 + threadIdx.x;
    if (idx >= L * 512) return;
    int l = idx >> 9;
    int r = idx & 511;
    int c = r >> 7;
    int rr = r & 127;
    int nt = rr >> 6, lane = rr & 63;
    int o = nt * 32 + (lane & 31);
    int kg = lane >> 5;
    unsigned short v[8];
#pragma unroll
    for (int j = 0; j < 8; ++j) {
        int cin = c * 16 + kg * 8 + j;
        v[j] = f2bf(src[((size_t)l * 64 + o) * 64 + cin]);
    }
    uint4 u;
    u.x = v[0] | ((unsigned)v[1] << 16);
    u.y = v[2] | ((unsigned)v[3] << 16);
    u.z = v[4] | ((unsigned)v[5] << 16);
    u.w = v[6] | ((unsigned)v[7] << 16);
    *(uint4*)(dst + (size_t)idx * 8) = u;
}

// ---------------------------------------------------------------------------
// Pack up conv weights [256 o][64 cin][3][3] -> [36 chunk][8 nt][64][8] bf16
// ---------------------------------------------------------------------------
__global__ void pack_up(const float* __restrict__ src, unsigned short* __restrict__ dst) {
    int idx = blockIdx.x * 256 + threadIdx.x;
    if (idx >= 18432) return;
    int c = idx >> 9;
    int nt = (idx >> 6) & 7;
    int lane = idx & 63;
    int o = nt * 32 + (lane & 31);
    int kg = lane >> 5;
    unsigned short v[8];
#pragma unroll
    for (int j = 0; j < 8; ++j) {
        int k = c * 16 + kg * 8 + j;
        int t = k >> 6, cin = k & 63;
        v[j] = f2bf(src[((size_t)o * 64 + cin) * 9 + t]);
    }
    uint4 u;
    u.x = v[0] | ((unsigned)v[1] << 16);
    u.y = v[2] | ((unsigned)v[3] << 16);
    u.z = v[4] | ((unsigned)v[5] << 16);
    u.w = v[6] | ((unsigned)v[7] << 16);
    *(uint4*)(dst + (size_t)idx * 8) = u;
}

// ---------------------------------------------------------------------------
// Pack tail conv weights [3 o][64 cin][3][3] -> [36 chunk][64 lane][8] bf16
// N padded 3 -> 32 with zeros (single N-tile).
// ---------------------------------------------------------------------------
__global__ void pack_tail(const float* __restrict__ src, unsigned short* __restrict__ dst) {
    int idx = blockIdx.x * 256 + threadIdx.x;
    if (idx >= 2304) return;
    int c = idx >> 6;
    int lane = idx & 63;
    int o = lane & 31;
    int kg = lane >> 5;
    unsigned short v[8];
#pragma unroll
    for (int j = 0; j < 8; ++j) {
        int k = c * 16 + kg * 8 + j;
        int t = k >> 6, cin = k & 63;
        v[j] = (o < 3) ? f2bf(src[((size_t)o * 64 + cin) * 9 + t]) : (unsigned short)0;
    }
    uint4 u;
    u.x = v[0] | ((unsigned)v[1] << 16);
    u.y = v[2] | ((unsigned)v[3] << 16);
    u.z = v[4] | ((unsigned)v[5] << 16);
    u.w = v[6] | ((unsigned)v[7] << 16);
    *(uint4*)(dst + (size_t)idx * 8) = u;
}

// ---------------------------------------------------------------------------
// kv = lrelu(k_v @ comp_w.T)
// ---------------------------------------------------------------------------
__global__ void kv_kernel(const float* __restrict__ kvin, const float* __restrict__ comp_w,
                          float* __restrict__ kv) {
    int b = blockIdx.x, c = threadIdx.x;
    const float* a = kvin + b * 256;
    const float* w = comp_w + c * 256;
    float s = 0.f;
    for (int m = 0; m < 256; ++m) s += a[m] * w[m];
    kv[b * 64 + c] = lrelu_f(s);
}

// ---------------------------------------------------------------------------
// Per-(layer,batch) dynamic kernel + CA attention precompute.
// ker_all[l][b][tap][c]; att_all[l][b][c]
// ---------------------------------------------------------------------------
__global__ void kerprep(const float* __restrict__ kv, const float* __restrict__ kw1,
                        const float* __restrict__ kw2, const float* __restrict__ caw1,
                        const float* __restrict__ caw2, float* __restrict__ ker_all,
                        float* __restrict__ att_all) {
    int l = blockIdx.x >> 4;
    int b = blockIdx.x & 15;
    int c = threadIdx.x;
    __shared__ float kvb[64];
    __shared__ float t1[64];
    __shared__ float a1[8];
    kvb[c] = kv[b * 64 + c];
    __syncthreads();
    {
        const float* w1 = kw1 + (size_t)l * 4096 + c * 64;
        float s = 0.f;
        for (int j = 0; j < 64; ++j) s += kvb[j] * w1[j];
        t1[c] = lrelu_f(s);
    }
    if (c < 8) {
        const float* cw1 = caw1 + (size_t)l * 512 + c * 64;
        float s = 0.f;
        for (int j = 0; j < 64; ++j) s += kvb[j] * cw1[j];
        a1[c] = lrelu_f(s);
    }
    __syncthreads();
    const float* w2 = kw2 + (size_t)l * 576 * 64;
    for (int t = 0; t < 9; ++t) {
        const float* row = w2 + (size_t)(c * 9 + t) * 64;
        float s = 0.f;
        for (int j = 0; j < 64; ++j) s += t1[j] * row[j];
        ker_all[(((size_t)l * 16 + b) * 9 + t) * 64 + c] = s;
    }
    {
        const float* c2 = caw2 + (size_t)l * 512 + c * 8;
        float s = 0.f;
        for (int r = 0; r < 8; ++r) s += a1[r] * c2[r];
        att_all[((size_t)l * 16 + b) * 64 + c] = 1.f / (1.f + expf(-s));
    }
}

// ---------------------------------------------------------------------------
// Head conv: x NCHW [16,3,64,64] -> x0,res NHWC; wt:[27][64] (fp32 vector)
// ---------------------------------------------------------------------------
__global__ __launch_bounds__(256) void head_conv(const float* __restrict__ x,
                                                 const float* __restrict__ wt,
                                                 const float* __restrict__ bias,
                                                 float* __restrict__ x0,
                                                 float* __restrict__ res) {
    int t = threadIdx.x;
    int co = t & 63, q = t >> 6;
    int bid = blockIdx.x;
    int b = bid >> 7;
    int rem = bid & 127;
    int y = rem >> 1;
    int xs = (rem & 1) * 32 + q * 8;

    float bv = bias[co];
    float acc[8];
#pragma unroll
    for (int p = 0; p < 8; ++p) acc[p] = bv;

    int coff[10];
    bool cok[10];
#pragma unroll
    for (int i = 0; i < 10; ++i) {
        int col = xs - 1 + i;
        cok[i] = (col >= 0) && (col < 64);
        coff[i] = cok[i] ? col : 0;
    }
    for (int cin = 0; cin < 3; ++cin) {
#pragma unroll
        for (int ky = 0; ky < 3; ++ky) {
            int row = y + ky - 1;
            bool rok = (row >= 0) && (row < 64);
            const float* rp = x + ((size_t)(b * 3 + cin) * 64 + (rok ? row : 0)) * 64;
            float v[10];
#pragma unroll
            for (int i = 0; i < 10; ++i) v[i] = (rok && cok[i]) ? rp[coff[i]] : 0.f;
            const float* wp = wt + ((cin * 3 + ky) * 3) * 64 + co;
            float w0 = wp[0], w1 = wp[64], w2 = wp[128];
#pragma unroll
            for (int p = 0; p < 8; ++p) acc[p] += w0 * v[p] + w1 * v[p + 1] + w2 * v[p + 2];
        }
    }
    size_t ob = (((size_t)b * 64 + y) * 64 + xs) * 64 + co;
#pragma unroll
    for (int p = 0; p < 8; ++p) {
        x0[ob + (size_t)p * 64] = acc[p];
        res[ob + (size_t)p * 64] = acc[p];
    }
}

// ---------------------------------------------------------------------------
// MFMA 3x3 conv 64->64, NHWC fp32 in/out, bf16 compute.
// Tile 16 wide x 8 tall (128 px), halo 18x10=180 px, LDS stride 72 shorts.
// 4 waves; wave w = M-tile w (32 px) x 2 N-tiles. Grid 512 (2 blocks/CU).
// ---------------------------------------------------------------------------
__global__ __launch_bounds__(256) void conv3x3_mfma(const float* __restrict__ in,
                                                    const unsigned short* __restrict__ wp,
                                                    const float* __restrict__ bias,
                                                    const float* __restrict__ resid,
                                                    float* __restrict__ out, int act) {
    __shared__ unsigned short sm[180 * 72];
    int tid = threadIdx.x;
    int bid = blockIdx.x;
    int b = bid >> 5;
    int rem = bid & 31;
    int ty = rem >> 2, tx = rem & 3;
    const float* inb = in + (size_t)b * 262144;

    for (int i = tid; i < 2880; i += 256) {
        int px = i >> 4, c4 = i & 15;
        int hy = px / 18, hx = px - hy * 18;
        int row = ty * 8 + hy - 1, col = tx * 16 + hx - 1;
        float4 v = make_float4(0.f, 0.f, 0.f, 0.f);
        if (row >= 0 && row < 64 && col >= 0 && col < 64)
            v = *(const float4*)(inb + (((size_t)row * 64 + col) * 64 + c4 * 4));
        uint2 u;
        u.x = f2bf(v.x) | ((unsigned)f2bf(v.y) << 16);
        u.y = f2bf(v.z) | ((unsigned)f2bf(v.w) << 16);
        *(uint2*)&sm[px * 72 + c4 * 4] = u;
    }
    __syncthreads();

    int lane = tid & 63, w = tid >> 6;
    int l31 = lane & 31, kg8 = (lane >> 5) * 8;
    int p0 = w * 32 + l31;
    int ly0 = p0 >> 4, lx0 = p0 & 15;

    f16acc a0 = {0,0,0,0,0,0,0,0,0,0,0,0,0,0,0,0};
    f16acc a1 = a0;

#pragma unroll
    for (int t = 0; t < 9; ++t) {
        int tyt = t / 3, txt = t - tyt * 3;
        int base = ((ly0 + tyt) * 18 + lx0 + txt) * 72 + kg8;
#pragma unroll
        for (int cc = 0; cc < 4; ++cc) {
            int c = t * 4 + cc;
            bh8 A = *(const bh8*)&sm[base + cc * 16];
            bh8 B0 = *(const bh8*)&wp[((size_t)(c * 2 + 0) * 64 + lane) * 8];
            bh8 B1 = *(const bh8*)&wp[((size_t)(c * 2 + 1) * 64 + lane) * 8];
            MFMA32(a0, A, B0);
            MFMA32(a1, A, B1);
        }
    }

    float bias0 = bias[l31], bias1 = bias[32 + l31];
    int hi = lane >> 5;
    size_t outb = (size_t)b * 262144;
#pragma unroll
    for (int r = 0; r < 16; ++r) {
        int rowm = (r & 3) + 8 * (r >> 2) + 4 * hi;
        int m = w * 32 + rowm;
        int gy = ty * 8 + (m >> 4), gx = tx * 16 + (m & 15);
        size_t i0 = outb + (((size_t)gy * 64 + gx) * 64);
        float v0 = a0[r] + bias0, v1 = a1[r] + bias1;
        if (resid) {
            v0 += resid[i0 + l31];
            v1 += resid[i0 + 32 + l31];
        }
        if (act) { v0 = lrelu_f(v0); v1 = lrelu_f(v1); }
        out[i0 + l31] = v0;
        out[i0 + 32 + l31] = v1;
    }
}

// ---------------------------------------------------------------------------
// Fused DA_conv (MFMA): stage input halo bf16 -> depthwise 3x3 from LDS ->
// mid LDS -> 1x1 MFMA -> +cb + in*att -> lrelu.
// Tile 16x8, halo 180 px. Grid 512 (2 blocks/CU). LDS 44.3 KB.
// ---------------------------------------------------------------------------
__global__ __launch_bounds__(256) void da_mfma(const float* __restrict__ in,
                                               const unsigned short* __restrict__ wp,
                                               const float* __restrict__ cb,
                                               const float* __restrict__ kerT,
                                               const float* __restrict__ attv,
                                               float* __restrict__ out) {
    __shared__ unsigned short sm[(180 + 128) * 72];
    const int MIDOFF = 180 * 72;
    int tid = threadIdx.x;
    int bid = blockIdx.x;
    int b = bid >> 5;
    int rem = bid & 31;
    int ty = rem >> 2, tx = rem & 3;
    const float* inb = in + (size_t)b * 262144;

    for (int i = tid; i < 2880; i += 256) {
        int px = i >> 4, c4 = i & 15;
        int hy = px / 18, hx = px - hy * 18;
        int row = ty * 8 + hy - 1, col = tx * 16 + hx - 1;
        float4 v = make_float4(0.f, 0.f, 0.f, 0.f);
        if (row >= 0 && row < 64 && col >= 0 && col < 64)
            v = *(const float4*)(inb + (((size_t)row * 64 + col) * 64 + c4 * 4));
        uint2 u;
        u.x = f2bf(v.x) | ((unsigned)f2bf(v.y) << 16);
        u.y = f2bf(v.z) | ((unsigned)f2bf(v.w) << 16);
        *(uint2*)&sm[px * 72 + c4 * 4] = u;
    }
    __syncthreads();

    // depthwise from LDS: thread = (c, q); q handles rows 2q, 2q+1
    {
        int c = tid & 63, q = tid >> 6;
        const float* kb = kerT + (size_t)b * 576;
        float k[9];
#pragma unroll
        for (int t = 0; t < 9; ++t) k[t] = kb[t * 64 + c];
#pragma unroll
        for (int rr = 0; rr < 2; ++rr) {
            int ly = q * 2 + rr;
            float m[16];
#pragma unroll
            for (int xx = 0; xx < 16; ++xx) m[xx] = 0.f;
#pragma unroll
            for (int ky = 0; ky < 3; ++ky) {
                int hr = ly + ky;
                float v[18];
#pragma unroll
                for (int i = 0; i < 18; ++i) v[i] = bf2f(sm[(hr * 18 + i) * 72 + c]);
                float k0 = k[ky * 3], k1 = k[ky * 3 + 1], k2 = k[ky * 3 + 2];
#pragma unroll
                for (int xx = 0; xx < 16; ++xx) m[xx] += k0 * v[xx] + k1 * v[xx + 1] + k2 * v[xx + 2];
            }
#pragma unroll
            for (int xx = 0; xx < 16; ++xx)
                sm[MIDOFF + (ly * 16 + xx) * 72 + c] = f2bf(lrelu_f(m[xx]));
        }
    }
    __syncthreads();

    // 1x1 MFMA, K=64
    int lane = tid & 63, w = tid >> 6;
    int l31 = lane & 31, kg8 = (lane >> 5) * 8;
    int base = MIDOFF + (w * 32 + l31) * 72 + kg8;

    f16acc a0 = {0,0,0,0,0,0,0,0,0,0,0,0,0,0,0,0};
    f16acc a1 = a0;
#pragma unroll
    for (int cc = 0; cc < 4; ++cc) {
        bh8 A = *(const bh8*)&sm[base + cc * 16];
        bh8 B0 = *(const bh8*)&wp[((size_t)(cc * 2 + 0) * 64 + lane) * 8];
        bh8 B1 = *(const bh8*)&wp[((size_t)(cc * 2 + 1) * 64 + lane) * 8];
        MFMA32(a0, A, B0);
        MFMA32(a1, A, B1);
    }

    float cb0 = cb[l31], cb1 = cb[32 + l31];
    float at0 = attv[b * 64 + l31], at1 = attv[b * 64 + 32 + l31];
    int hi = lane >> 5;
    size_t outb = (size_t)b * 262144;
#pragma unroll
    for (int r = 0; r < 16; ++r) {
        int rowm = (r & 3) + 8 * (r >> 2) + 4 * hi;
        int m = w * 32 + rowm;
        int gy = ty * 8 + (m >> 4), gx = tx * 16 + (m & 15);
        size_t i0 = outb + (((size_t)gy * 64 + gx) * 64);
        float v0 = a0[r] + cb0 + in[i0 + l31] * at0;
        float v1 = a1[r] + cb1 + in[i0 + 32 + l31] * at1;
        out[i0 + l31] = lrelu_f(v0);
        out[i0 + 32 + l31] = lrelu_f(v1);
    }
}

// ---------------------------------------------------------------------------
// Up conv 64->256 (MFMA) + fused pixel shuffle. Tile 8x8 px, halo 10x10.
// Wave w: co [w*64, w*64+64). Grid 1024.
// ---------------------------------------------------------------------------
__global__ __launch_bounds__(256) void up_mfma(const float* __restrict__ in,
                                               const unsigned short* __restrict__ wp,
                                               const float* __restrict__ bias,
                                               float* __restrict__ shuf) {
    __shared__ unsigned short sm[100 * 72];
    int tid = threadIdx.x;
    int bid = blockIdx.x;
    int b = bid >> 6;
    int t6 = bid & 63;
    int ty = t6 >> 3, tx = t6 & 7;
    const float* inb = in + (size_t)b * 262144;

    for (int i = tid; i < 1600; i += 256) {
        int px = i >> 4, c4 = i & 15;
        int hy = px / 10, hx = px - hy * 10;
        int row = ty * 8 + hy - 1, col = tx * 8 + hx - 1;
        float4 v = make_float4(0.f, 0.f, 0.f, 0.f);
        if (row >= 0 && row < 64 && col >= 0 && col < 64)
            v = *(const float4*)(inb + (((size_t)row * 64 + col) * 64 + c4 * 4));
        uint2 u;
        u.x = f2bf(v.x) | ((unsigned)f2bf(v.y) << 16);
        u.y = f2bf(v.z) | ((unsigned)f2bf(v.w) << 16);
        *(uint2*)&sm[px * 72 + c4 * 4] = u;
    }
    __syncthreads();

    int lane = tid & 63, w = tid >> 6;
    int l31 = lane & 31, kg8 = (lane >> 5) * 8;
    int ly0 = l31 >> 3, lx0 = l31 & 7;

    f16acc a00 = {0,0,0,0,0,0,0,0,0,0,0,0,0,0,0,0};
    f16acc a01 = a00, a10 = a00, a11 = a00;

#pragma unroll
    for (int t = 0; t < 9; ++t) {
        int tyt = t / 3, txt = t - tyt * 3;
        int base0 = ((ly0 + tyt) * 10 + lx0 + txt) * 72 + kg8;
        int base1 = base0 + 2880;  // +32 px = +4 halo rows
#pragma unroll
        for (int cc = 0; cc < 4; ++cc) {
            int c = t * 4 + cc;
            bh8 A0 = *(const bh8*)&sm[base0 + cc * 16];
            bh8 A1 = *(const bh8*)&sm[base1 + cc * 16];
            bh8 B0 = *(const bh8*)&wp[((size_t)(c * 8 + w * 2 + 0) * 64 + lane) * 8];
            bh8 B1 = *(const bh8*)&wp[((size_t)(c * 8 + w * 2 + 1) * 64 + lane) * 8];
            MFMA32(a00, A0, B0);
            MFMA32(a01, A0, B1);
            MFMA32(a10, A1, B0);
            MFMA32(a11, A1, B1);
        }
    }

    int co0 = w * 64 + l31, co1 = co0 + 32;
    float bias0 = bias[co0], bias1 = bias[co1];
    int ch0 = co0 >> 2, r10 = (co0 >> 1) & 1, r20 = co0 & 1;
    int ch1 = co1 >> 2, r11 = (co1 >> 1) & 1, r21 = co1 & 1;
    int hi = lane >> 5;
#pragma unroll
    for (int r = 0; r < 16; ++r) {
        int rowm = (r & 3) + 8 * (r >> 2) + 4 * hi;
#pragma unroll
        for (int mt = 0; mt < 2; ++mt) {
            int m = mt * 32 + rowm;
            int y = ty * 8 + (m >> 3), x = tx * 8 + (m & 7);
            float va = (mt == 0) ? a00[r] : a10[r];
            float vb = (mt == 0) ? a01[r] : a11[r];
            shuf[(((size_t)b * 128 + 2 * y + r10) * 128 + 2 * x + r20) * 64 + ch0] = va + bias0;
            shuf[(((size_t)b * 128 + 2 * y + r11) * 128 + 2 * x + r21) * 64 + ch1] = vb + bias1;
        }
    }
}

// ---------------------------------------------------------------------------
// Tail conv 64->3 as MFMA with N padded to 32. shuf [16,128,128,64] NHWC ->
// out NCHW [16,3,128,128]. Tile 16x16, halo 18x18. Grid 1024.
// Wave w: M-tiles {2w, 2w+1} x 1 N-tile; only lanes with col<3 store.
// ---------------------------------------------------------------------------
__global__ __launch_bounds__(256) void tail_mfma(const float* __restrict__ shuf,
                                                 const unsigned short* __restrict__ wp,
                                                 const float* __restrict__ bias,
                                                 float* __restrict__ outp) {
    __shared__ unsigned short sm[324 * 72];
    int tid = threadIdx.x;
    int bid = blockIdx.x;
    int b = bid >> 6;
    int rem = bid & 63;
    int ty = rem >> 3, tx = rem & 7;
    const float* sb = shuf + (size_t)b * 128 * 128 * 64;

    for (int i = tid; i < 5184; i += 256) {
        int px = i >> 4, c4 = i & 15;
        int hy = px / 18, hx = px - hy * 18;
        int row = ty * 16 + hy - 1, col = tx * 16 + hx - 1;
        float4 v = make_float4(0.f, 0.f, 0.f, 0.f);
        if (row >= 0 && row < 128 && col >= 0 && col < 128)
            v = *(const float4*)(sb + (((size_t)row * 128 + col) * 64 + c4 * 4));
        uint2 u;
        u.x = f2bf(v.x) | ((unsigned)f2bf(v.y) << 16);
        u.y = f2bf(v.z) | ((unsigned)f2bf(v.w) << 16);
        *(uint2*)&sm[px * 72 + c4 * 4] = u;
    }
    __syncthreads();

    int lane = tid & 63, w = tid >> 6;
    int l31 = lane & 31, kg8 = (lane >> 5) * 8;
    int mbase = w * 64;
    int p0 = mbase + l31;
    int ly0 = p0 >> 4, lx0 = p0 & 15;

    f16acc a0 = {0,0,0,0,0,0,0,0,0,0,0,0,0,0,0,0};
    f16acc a1 = a0;

#pragma unroll
    for (int t = 0; t < 9; ++t) {
        int tyt = t / 3, txt = t - tyt * 3;
        int base0 = ((ly0 + tyt) * 18 + lx0 + txt) * 72 + kg8;
        int base1 = base0 + 2592;  // +32 px = +2 halo rows
#pragma unroll
        for (int cc = 0; cc < 4; ++cc) {
            int c = t * 4 + cc;
            bh8 A0 = *(const bh8*)&sm[base0 + cc * 16];
            bh8 A1 = *(const bh8*)&sm[base1 + cc * 16];
            bh8 B = *(const bh8*)&wp[((size_t)c * 64 + lane) * 8];
            MFMA32(a0, A0, B);
            MFMA32(a1, A1, B);
        }
    }

    if (l31 < 3) {
        float bv = bias[l31];
        int hi = lane >> 5;
        size_t ob = ((size_t)b * 3 + l31) * 16384;
#pragma unroll
        for (int r = 0; r < 16; ++r) {
            int rowm = (r & 3) + 8 * (r >> 2) + 4 * hi;
            int m0 = mbase + rowm;
            int gy0 = ty * 16 + (m0 >> 4), gx0 = tx * 16 + (m0 & 15);
            outp[ob + (size_t)gy0 * 128 + gx0] = a0[r] + bv;
            int m1 = m0 + 32;
            int gy1 = ty * 16 + (m1 >> 4), gx1 = tx * 16 + (m1 & 15);
            outp[ob + (size_t)gy1 * 128 + gx1] = a1[r] + bv;
        }
    }
}

// ---------------------------------------------------------------------------
extern "C" void kernel_launch(void* const* d_in, const int* in_sizes, int n_in,
                              void* d_out, int out_size, void* d_ws, size_t ws_size,
                              hipStream_t stream) {
    const float* x      = (const float*)d_in[0];
    const float* k_v    = (const float*)d_in[1];
    const float* head_w = (const float*)d_in[2];
    const float* head_b = (const float*)d_in[3];
    const float* comp_w = (const float*)d_in[4];
    const float* da_kw1 = (const float*)d_in[5];
    const float* da_kw2 = (const float*)d_in[6];
    const float* da_cw  = (const float*)d_in[7];
    const float* da_cb  = (const float*)d_in[8];
    const float* ca_w1  = (const float*)d_in[9];
    const float* ca_w2  = (const float*)d_in[10];
    const float* dab_cw = (const float*)d_in[11];
    const float* dab_cb = (const float*)d_in[12];
    const float* grp_w  = (const float*)d_in[13];
    const float* grp_b  = (const float*)d_in[14];
    const float* body_w = (const float*)d_in[15];
    const float* body_b = (const float*)d_in[16];
    const float* up_w   = (const float*)d_in[17];
    const float* up_b   = (const float*)d_in[18];
    const float* tail_w = (const float*)d_in[19];
    const float* tail_b = (const float*)d_in[20];

    char* base = (char*)d_ws;
    auto alloc = [&](size_t bytes) -> char* {
        char* p = base;
        base += (bytes + 255) & ~(size_t)255;
        return p;
    };
    unsigned short* wp_dab  = (unsigned short*)alloc((size_t)50 * 36864 * 2);
    unsigned short* wp_grp  = (unsigned short*)alloc((size_t)5 * 36864 * 2);
    unsigned short* wp_body = (unsigned short*)alloc((size_t)36864 * 2);
    unsigned short* wp_up   = (unsigned short*)alloc((size_t)147456 * 2);
    unsigned short* wp_da   = (unsigned short*)alloc((size_t)50 * 4096 * 2);
    unsigned short* wp_tail = (unsigned short*)alloc((size_t)18432 * 2);
    float* wT_head = (float*)alloc(1728 * 4);
    float* kvbuf   = (float*)alloc(1024 * 4);
    float* ker_all = (float*)alloc((size_t)460800 * 4);
    float* att_all = (float*)alloc((size_t)51200 * 4);
    const size_t ACT = (size_t)16 * 64 * 64 * 64;
    float* x0  = (float*)alloc(ACT * 4);
    float* b0  = (float*)alloc(ACT * 4);
    float* b1  = (float*)alloc(ACT * 4);
    float* b2  = (float*)alloc(ACT * 4);
    float* t0b = (float*)alloc(ACT * 4);
    float* t1b = (float*)alloc(ACT * 4);
    float* shuf = (float*)alloc((size_t)16 * 128 * 128 * 64 * 4);

    pack3x3<<<900, 256, 0, stream>>>(dab_cw, wp_dab, 50);
    pack3x3<<<90, 256, 0, stream>>>(grp_w, wp_grp, 5);
    pack3x3<<<18, 256, 0, stream>>>(body_w, wp_body, 1);
    pack_da<<<100, 256, 0, stream>>>(da_cw, wp_da, 50);
    pack_up<<<72, 256, 0, stream>>>(up_w, wp_up);
    pack_tail<<<9, 256, 0, stream>>>(tail_w, wp_tail);
    transpose_w<<<7, 256, 0, stream>>>(head_w, wT_head, 1, 64, 27);

    kv_kernel<<<16, 64, 0, stream>>>(k_v, comp_w, kvbuf);
    kerprep<<<800, 64, 0, stream>>>(kvbuf, da_kw1, da_kw2, ca_w1, ca_w2, ker_all, att_all);

    head_conv<<<2048, 256, 0, stream>>>(x, wT_head, head_b, x0, b0);

    for (int g = 0; g < 5; ++g) {
        float* rin = b0;  // group input, preserved until group tail
        for (int n = 0; n < 5; ++n) {
            int l0 = (g * 5 + n) * 2, l1 = l0 + 1;
            da_mfma<<<512, 256, 0, stream>>>(rin, wp_da + (size_t)l0 * 4096,
                                             da_cb + (size_t)l0 * 64, ker_all + (size_t)l0 * 9216,
                                             att_all + (size_t)l0 * 1024, t0b);
            conv3x3_mfma<<<512, 256, 0, stream>>>(t0b, wp_dab + (size_t)l0 * 36864,
                                                  dab_cb + (size_t)l0 * 64, nullptr, t1b, 1);
            da_mfma<<<512, 256, 0, stream>>>(t1b, wp_da + (size_t)l1 * 4096,
                                             da_cb + (size_t)l1 * 64, ker_all + (size_t)l1 * 9216,
                                             att_all + (size_t)l1 * 1024, t0b);
            float* rout = (rin == b1) ? b2 : b1;
            conv3x3_mfma<<<512, 256, 0, stream>>>(t0b, wp_dab + (size_t)l1 * 36864,
                                                  dab_cb + (size_t)l1 * 64, rin, rout, 0);
            rin = rout;
        }
        float* gout = (rin == b1) ? b2 : b1;
        conv3x3_mfma<<<512, 256, 0, stream>>>(rin, wp_grp + (size_t)g * 36864,
                                              grp_b + (size_t)g * 64, b0, gout, 0);
        // rotate: new group input = gout; keep all three distinct
        float* ob0 = b0;
        b0 = gout;
        b1 = ob0;
        b2 = rin;
    }
    conv3x3_mfma<<<512, 256, 0, stream>>>(b0, wp_body, body_b, x0, b1, 0);

    up_mfma<<<1024, 256, 0, stream>>>(b1, wp_up, up_b, shuf);
    tail_mfma<<<1024, 256, 0, stream>>>(shuf, wp_tail, tail_b, (float*)d_out);
}